// Round 1
// baseline (1028.136 us; speedup 1.0000x reference)
//
#include <hip/hip_runtime.h>
#include <hip/hip_bf16.h>
#include <math.h>

#define B_   2
#define T_   2048
#define D_   768
#define H_   12
#define DH_  64
#define IH_  4
#define ID_  64
#define K_   64
#define M_   (B_ * T_)        // 4096
#define NQKV 2304

#define LDT 132               // padded LDS row stride (floats)

// ---------------------------------------------------------------------------
// Tiled fp32 GEMM body: C[M,N] = A[M,Kd] @ W[N,Kd]^T + bias
// 128x128 tile, 256 threads, 8x8 per thread, BK=32, LDS staged transposed.
// ---------------------------------------------------------------------------
__device__ __forceinline__ void gemm_tile_body(
    const float* __restrict__ A, const float* __restrict__ W,
    const float* __restrict__ bias, float* __restrict__ C,
    int Nn, int Kd, int bm, int bn,
    float (*la)[LDT], float (*lb)[LDT])
{
    const int tid = threadIdx.x;
    const int tx = tid & 15;        // 16 col-groups
    const int ty = tid >> 4;        // 16 row-groups

    float acc[8][8];
#pragma unroll
    for (int i = 0; i < 8; ++i)
#pragma unroll
        for (int j = 0; j < 8; ++j) acc[i][j] = 0.0f;

    for (int k0 = 0; k0 < Kd; k0 += 32) {
#pragma unroll
        for (int i = 0; i < 4; ++i) {
            int f4 = tid + (i << 8);
            int r = f4 >> 3;        // 0..127
            int cq = f4 & 7;        // 0..7 (float4 within 32-col chunk)
            float4 a = *(const float4*)(A + (size_t)(bm + r) * Kd + k0 + (cq << 2));
            la[cq * 4 + 0][r] = a.x;
            la[cq * 4 + 1][r] = a.y;
            la[cq * 4 + 2][r] = a.z;
            la[cq * 4 + 3][r] = a.w;
            float4 w = *(const float4*)(W + (size_t)(bn + r) * Kd + k0 + (cq << 2));
            lb[cq * 4 + 0][r] = w.x;
            lb[cq * 4 + 1][r] = w.y;
            lb[cq * 4 + 2][r] = w.z;
            lb[cq * 4 + 3][r] = w.w;
        }
        __syncthreads();
#pragma unroll
        for (int kk = 0; kk < 32; ++kk) {
            float4 a0 = *(const float4*)&la[kk][ty * 8];
            float4 a1 = *(const float4*)&la[kk][ty * 8 + 4];
            float4 b0 = *(const float4*)&lb[kk][tx * 8];
            float4 b1 = *(const float4*)&lb[kk][tx * 8 + 4];
            float av[8] = {a0.x, a0.y, a0.z, a0.w, a1.x, a1.y, a1.z, a1.w};
            float bv[8] = {b0.x, b0.y, b0.z, b0.w, b1.x, b1.y, b1.z, b1.w};
#pragma unroll
            for (int i = 0; i < 8; ++i)
#pragma unroll
                for (int j = 0; j < 8; ++j)
                    acc[i][j] = fmaf(av[i], bv[j], acc[i][j]);
        }
        __syncthreads();
    }

    // epilogue
    float bsv[8];
    {
        float4 q0 = *(const float4*)(bias + bn + tx * 8);
        float4 q1 = *(const float4*)(bias + bn + tx * 8 + 4);
        bsv[0] = q0.x; bsv[1] = q0.y; bsv[2] = q0.z; bsv[3] = q0.w;
        bsv[4] = q1.x; bsv[5] = q1.y; bsv[6] = q1.z; bsv[7] = q1.w;
    }
#pragma unroll
    for (int i = 0; i < 8; ++i) {
        int rr = bm + ty * 8 + i;
        float* cp = C + (size_t)rr * Nn + bn + tx * 8;
        float4 o0, o1;
        o0.x = acc[i][0] + bsv[0]; o0.y = acc[i][1] + bsv[1];
        o0.z = acc[i][2] + bsv[2]; o0.w = acc[i][3] + bsv[3];
        o1.x = acc[i][4] + bsv[4]; o1.y = acc[i][5] + bsv[5];
        o1.z = acc[i][6] + bsv[6]; o1.w = acc[i][7] + bsv[7];
        *(float4*)cp = o0;
        *(float4*)(cp + 4) = o1;
    }
}

__global__ __launch_bounds__(256) void gemm_f32(
    const float* __restrict__ A, const float* __restrict__ W,
    const float* __restrict__ bias, float* __restrict__ C, int Nn, int Kd)
{
    __shared__ float la[32][LDT];
    __shared__ float lb[32][LDT];
    gemm_tile_body(A, W, bias, C, Nn, Kd, blockIdx.y * 128, blockIdx.x * 128, la, lb);
}

// qI and kI fused in one launch (128 blocks instead of 2x64)
__global__ __launch_bounds__(256) void gemm_qiki(
    const float* __restrict__ x,
    const float* __restrict__ wq, const float* __restrict__ bq,
    const float* __restrict__ wk, const float* __restrict__ bk,
    float* __restrict__ qI, float* __restrict__ kI)
{
    __shared__ float la[32][LDT];
    __shared__ float lb[32][LDT];
    if (blockIdx.x < 2)
        gemm_tile_body(x, wq, bq, qI, IH_ * ID_, D_, blockIdx.y * 128, blockIdx.x * 128, la, lb);
    else
        gemm_tile_body(x, wk, bk, kI, IH_ * ID_, D_, blockIdx.y * 128, (blockIdx.x - 2) * 128, la, lb);
}

// ---------------------------------------------------------------------------
// Indexer scores: scores[b][t][s] = sum_h w_head[h] * relu(qI[b,t,h,:] . kI[b,s,h,:])
// 128x128 (t,s) tile per block; skip tiles entirely above the diagonal.
// ---------------------------------------------------------------------------
__global__ __launch_bounds__(256) void scores_kernel(
    const float* __restrict__ qI, const float* __restrict__ kI,
    const float* __restrict__ w_head, float* __restrict__ scores)
{
    const int is = blockIdx.x, it = blockIdx.y, b = blockIdx.z;
    if (is > it) return;
    __shared__ float lq[32][LDT];
    __shared__ float lk[32][LDT];
    const int tid = threadIdx.x;
    const int tx = tid & 15, ty = tid >> 4;
    const int t0 = it * 128, s0 = is * 128;

    float sc[8][8];
#pragma unroll
    for (int i = 0; i < 8; ++i)
#pragma unroll
        for (int j = 0; j < 8; ++j) sc[i][j] = 0.0f;

    for (int h = 0; h < IH_; ++h) {
        float rel[8][8];
#pragma unroll
        for (int i = 0; i < 8; ++i)
#pragma unroll
            for (int j = 0; j < 8; ++j) rel[i][j] = 0.0f;

        for (int k0 = 0; k0 < ID_; k0 += 32) {
#pragma unroll
            for (int i = 0; i < 4; ++i) {
                int f4 = tid + (i << 8);
                int r = f4 >> 3;
                int cq = f4 & 7;
                float4 a = *(const float4*)(qI + (size_t)(b * T_ + t0 + r) * (IH_ * ID_) + h * ID_ + k0 + (cq << 2));
                lq[cq * 4 + 0][r] = a.x;
                lq[cq * 4 + 1][r] = a.y;
                lq[cq * 4 + 2][r] = a.z;
                lq[cq * 4 + 3][r] = a.w;
                float4 c = *(const float4*)(kI + (size_t)(b * T_ + s0 + r) * (IH_ * ID_) + h * ID_ + k0 + (cq << 2));
                lk[cq * 4 + 0][r] = c.x;
                lk[cq * 4 + 1][r] = c.y;
                lk[cq * 4 + 2][r] = c.z;
                lk[cq * 4 + 3][r] = c.w;
            }
            __syncthreads();
#pragma unroll
            for (int kk = 0; kk < 32; ++kk) {
                float4 a0 = *(const float4*)&lq[kk][ty * 8];
                float4 a1 = *(const float4*)&lq[kk][ty * 8 + 4];
                float4 b0 = *(const float4*)&lk[kk][tx * 8];
                float4 b1 = *(const float4*)&lk[kk][tx * 8 + 4];
                float av[8] = {a0.x, a0.y, a0.z, a0.w, a1.x, a1.y, a1.z, a1.w};
                float bv[8] = {b0.x, b0.y, b0.z, b0.w, b1.x, b1.y, b1.z, b1.w};
#pragma unroll
                for (int i = 0; i < 8; ++i)
#pragma unroll
                    for (int j = 0; j < 8; ++j)
                        rel[i][j] = fmaf(av[i], bv[j], rel[i][j]);
            }
            __syncthreads();
        }
        float wh = w_head[h];
#pragma unroll
        for (int i = 0; i < 8; ++i)
#pragma unroll
            for (int j = 0; j < 8; ++j)
                sc[i][j] += wh * fmaxf(rel[i][j], 0.0f);
    }

#pragma unroll
    for (int i = 0; i < 8; ++i) {
        int tt = t0 + ty * 8 + i;
        float* sp = scores + ((size_t)b * T_ + tt) * T_ + s0 + tx * 8;
        float4 o0 = {sc[i][0], sc[i][1], sc[i][2], sc[i][3]};
        float4 o1 = {sc[i][4], sc[i][5], sc[i][6], sc[i][7]};
        *(float4*)sp = o0;
        *(float4*)(sp + 4) = o1;
    }
}

// ---------------------------------------------------------------------------
// Top-64 per causal row via 64 rounds of block argmax extraction.
// Tie-break: smaller index wins (matches jax.lax.top_k; matters for exact-0.0
// scores which occur when all 4 relu'd inner products are <=0).
// ---------------------------------------------------------------------------
__global__ __launch_bounds__(256) void topk_kernel(
    const float* __restrict__ scores, int* __restrict__ idx_out,
    float* __restrict__ rout_out)
{
    const int row = blockIdx.x;          // b*T + t
    const int b = row >> 11;
    const int t = row & (T_ - 1);
    const int tid = threadIdx.x;
    const int n = t + 1;
    const int nv = n < K_ ? n : K_;

    __shared__ float vals[T_];
    __shared__ float rv[4];
    __shared__ int ri[4];

    const float* srow = scores + ((size_t)b * T_ + t) * T_;
    for (int s = tid; s < n; s += 256) vals[s] = srow[s];
    __syncthreads();

    for (int r = 0; r < nv; ++r) {
        float bv = -INFINITY;
        int bi = 0x7fffffff;
        for (int s = tid; s < n; s += 256) {
            float v = vals[s];
            if (v > bv) { bv = v; bi = s; }   // ascending scan keeps smallest idx on ties
        }
#pragma unroll
        for (int off = 32; off; off >>= 1) {
            float v2 = __shfl_down(bv, off);
            int i2 = __shfl_down(bi, off);
            if (v2 > bv || (v2 == bv && i2 < bi)) { bv = v2; bi = i2; }
        }
        if ((tid & 63) == 0) { rv[tid >> 6] = bv; ri[tid >> 6] = bi; }
        __syncthreads();
        if (tid == 0) {
#pragma unroll
            for (int w = 1; w < 4; ++w) {
                if (rv[w] > bv || (rv[w] == bv && ri[w] < bi)) { bv = rv[w]; bi = ri[w]; }
            }
            idx_out[(size_t)row * K_ + r] = bi;
            rout_out[(size_t)row * K_ + r] = bv;
            vals[bi] = -INFINITY;
        }
        __syncthreads();
    }
    for (int r = nv + tid; r < K_; r += 256) {
        idx_out[(size_t)row * K_ + r] = 0;
        rout_out[(size_t)row * K_ + r] = 0.0f;
    }
}

// ---------------------------------------------------------------------------
// Sparse attention: per (b,t) block; wave w handles heads {w, w+4, w+8};
// lane = k for QK^T + softmax, lane = d for PV.
// ---------------------------------------------------------------------------
__global__ __launch_bounds__(256) void attn_kernel(
    const float* __restrict__ qkv, const int* __restrict__ idx,
    const float* __restrict__ routing, float* __restrict__ attout)
{
    const int row = blockIdx.x;          // m = b*T + t
    const int b = row >> 11;
    const int t = row & (T_ - 1);
    const int tid = threadIdx.x;
    const int lane = tid & 63;
    const int wave = tid >> 6;
    const int nv = (t + 1) < K_ ? (t + 1) : K_;

    __shared__ float qs[D_];
    for (int i = tid; i < D_; i += 256) qs[i] = qkv[(size_t)row * NQKV + i];

    int myidx = 0;
    float myrout = 0.0f;
    if (lane < nv) {
        myidx = idx[(size_t)row * K_ + lane];
        myrout = routing[(size_t)row * K_ + lane];
    }
    __syncthreads();

    const float scale = 0.125f;          // 1/sqrt(64)
#pragma unroll
    for (int hh = 0; hh < 3; ++hh) {
        const int h = wave + hh * 4;
        // QK^T
        float att = -INFINITY;
        if (lane < nv) {
            const float* kp = qkv + (size_t)(b * T_ + myidx) * NQKV + D_ + h * DH_;
            const float* qp = qs + h * DH_;
            float acc = 0.0f;
#pragma unroll
            for (int d4 = 0; d4 < 16; ++d4) {
                float4 kv4 = *(const float4*)(kp + d4 * 4);
                float4 q4 = *(const float4*)(qp + d4 * 4);
                acc = fmaf(kv4.x, q4.x, acc);
                acc = fmaf(kv4.y, q4.y, acc);
                acc = fmaf(kv4.z, q4.z, acc);
                acc = fmaf(kv4.w, q4.w, acc);
            }
            att = acc * scale;
        }
        // softmax over 64 lanes (invalid lanes contribute 0)
        float m = att;
#pragma unroll
        for (int off = 32; off; off >>= 1) m = fmaxf(m, __shfl_xor(m, off));
        float e = (lane < nv) ? __expf(att - m) : 0.0f;
        float ssum = e;
#pragma unroll
        for (int off = 32; off; off >>= 1) ssum += __shfl_xor(ssum, off);
        float p = e / ssum * myrout;

        // PV: lane = d
        float acc = 0.0f;
        for (int k = 0; k < nv; ++k) {
            float pk = __shfl(p, k);
            int ik = __shfl(myidx, k);
            acc = fmaf(pk, qkv[(size_t)(b * T_ + ik) * NQKV + 2 * D_ + h * DH_ + lane], acc);
        }
        attout[(size_t)row * D_ + h * DH_ + lane] = acc;
    }
}

// ---------------------------------------------------------------------------
extern "C" void kernel_launch(void* const* d_in, const int* in_sizes, int n_in,
                              void* d_out, int out_size, void* d_ws, size_t ws_size,
                              hipStream_t stream)
{
    const float* x      = (const float*)d_in[0];
    const float* wq_i   = (const float*)d_in[1];
    const float* bq_i   = (const float*)d_in[2];
    const float* wk_i   = (const float*)d_in[3];
    const float* bk_i   = (const float*)d_in[4];
    const float* w_head = (const float*)d_in[5];
    const float* w_qkv  = (const float*)d_in[6];
    const float* b_qkv  = (const float*)d_in[7];
    const float* w_out  = (const float*)d_in[8];
    const float* b_out  = (const float*)d_in[9];
    float* out = (float*)d_out;

    float* ws = (float*)d_ws;
    float* qkv     = ws;                                   // M x 2304
    float* qI      = qkv + (size_t)M_ * NQKV;              // M x 256
    float* kI      = qI + (size_t)M_ * (IH_ * ID_);        // M x 256
    float* attout  = kI + (size_t)M_ * (IH_ * ID_);        // M x 768
    float* routing = attout + (size_t)M_ * D_;             // M x 64
    float* scoresb = routing + (size_t)M_ * K_;            // B x T x T
    int*   idxb    = (int*)(scoresb + (size_t)B_ * T_ * T_); // M x 64

    dim3 blk(256);
    gemm_f32<<<dim3(NQKV / 128, M_ / 128), blk, 0, stream>>>(x, w_qkv, b_qkv, qkv, NQKV, D_);
    gemm_qiki<<<dim3(4, M_ / 128), blk, 0, stream>>>(x, wq_i, bq_i, wk_i, bk_i, qI, kI);
    scores_kernel<<<dim3(T_ / 128, T_ / 128, B_), blk, 0, stream>>>(qI, kI, w_head, scoresb);
    topk_kernel<<<dim3(M_), blk, 0, stream>>>(scoresb, idxb, routing);
    attn_kernel<<<dim3(M_), blk, 0, stream>>>(qkv, idxb, routing, attout);
    gemm_f32<<<dim3(D_ / 128, M_ / 128), blk, 0, stream>>>(attout, w_out, b_out, out, D_, D_);
}

// Round 6
// 744.467 us; speedup vs baseline: 1.3810x; 1.3810x over previous
//
#include <hip/hip_runtime.h>
#include <hip/hip_bf16.h>
#include <math.h>

#define B_   2
#define T_   2048
#define D_   768
#define H_   12
#define DH_  64
#define IH_  4
#define ID_  64
#define K_   64
#define M_   (B_ * T_)        // 4096
#define NQKV 2304

#define LDT 132               // padded LDS row stride (floats)

typedef __attribute__((ext_vector_type(8))) short bf16x8;
typedef __attribute__((ext_vector_type(4))) float f32x4;

#define GLOBAL_AS __attribute__((address_space(1)))
#define LDS_AS    __attribute__((address_space(3)))

// ---------------------------------------------------------------------------
// fp32 -> (hi,lo) bf16 split.  x ~= hi + lo with ~16-17 mantissa bits kept.
// ---------------------------------------------------------------------------
__device__ __forceinline__ void split2(float f, unsigned short& h, unsigned short& l)
{
    __bf16 b = (__bf16)f;
    h = __builtin_bit_cast(unsigned short, b);
    __bf16 c = (__bf16)(f - (float)b);
    l = __builtin_bit_cast(unsigned short, c);
}

__global__ __launch_bounds__(256) void split_kernel(
    const float* __restrict__ in, unsigned short* __restrict__ hi,
    unsigned short* __restrict__ lo, int n4)
{
    int i = blockIdx.x * 256 + threadIdx.x;
    if (i >= n4) return;
    float4 v = ((const float4*)in)[i];
    ushort4 hv, lv;
    split2(v.x, hv.x, lv.x);
    split2(v.y, hv.y, lv.y);
    split2(v.z, hv.z, lv.z);
    split2(v.w, hv.w, lv.w);
    ((ushort4*)hi)[i] = hv;
    ((ushort4*)lo)[i] = lv;
}

// ---------------------------------------------------------------------------
// Split-bf16 MFMA GEMM:  C[M,Nn] = A @ W^T + bias   (A = Ahi+Alo, W = Whi+Wlo)
// Computes Ahi*Whi + Ahi*Wlo + Alo*Whi via 36 K-tiles of 64 (3 phases x 768).
// 128x128 tile, 4 waves (each 64x64 = 4x4 frags of 16x16x32 bf16 MFMA).
// global_load_lds width 16 with pre-swizzled global source; XOR-swizzled
// LDS reads (byte ^= (row&7)<<4) kill the stride-128B bank conflict.
// ---------------------------------------------------------------------------
__global__ __launch_bounds__(256) void gemm_bf16split(
    const unsigned short* __restrict__ Ahi, const unsigned short* __restrict__ Alo,
    const unsigned short* __restrict__ Whi, const unsigned short* __restrict__ Wlo,
    const float* __restrict__ bias, float* __restrict__ C, int Nn)
{
    __shared__ char lsa[128 * 128];
    __shared__ char lsb[128 * 128];
    const int tid = threadIdx.x;
    const int lane = tid & 63;
    const int wv = tid >> 6;
    const int bm = blockIdx.y * 128, bn = blockIdx.x * 128;
    const int wr = (wv >> 1) * 64, wc = (wv & 1) * 64;

    f32x4 acc[4][4];
    const f32x4 zero = {0.0f, 0.0f, 0.0f, 0.0f};
#pragma unroll
    for (int m = 0; m < 4; ++m)
#pragma unroll
        for (int n = 0; n < 4; ++n) acc[m][n] = zero;

    const int srow = lane >> 3;           // row within an 8-row staging call
    const int scol = (lane & 7) * 16;     // byte col within 128B row

    for (int kt = 0; kt < 36; ++kt) {
        const unsigned short* Ap;
        const unsigned short* Wp;
        int kc;
        if (kt < 12)      { Ap = Ahi; Wp = Whi; kc = kt * 64; }
        else if (kt < 24) { Ap = Ahi; Wp = Wlo; kc = (kt - 12) * 64; }
        else              { Ap = Alo; Wp = Whi; kc = (kt - 24) * 64; }

#pragma unroll
        for (int i = 0; i < 4; ++i) {
            int rl = wv * 32 + i * 8 + srow;               // local row 0..127
            int sb = scol ^ ((rl & 7) << 4);               // inverse-swizzled src
            const char* ga = (const char*)Ap + ((size_t)(bm + rl) * D_ + kc) * 2 + sb;
            __builtin_amdgcn_global_load_lds((GLOBAL_AS const void*)ga,
                (LDS_AS void*)(lsa + (wv * 32 + i * 8) * 128), 16, 0, 0);
            const char* gb = (const char*)Wp + ((size_t)(bn + rl) * D_ + kc) * 2 + sb;
            __builtin_amdgcn_global_load_lds((GLOBAL_AS const void*)gb,
                (LDS_AS void*)(lsb + (wv * 32 + i * 8) * 128), 16, 0, 0);
        }
        __syncthreads();

#pragma unroll
        for (int ks = 0; ks < 2; ++ks) {
            bf16x8 afr[4], bfr[4];
            const int kb = ks * 64 + ((lane >> 4) * 16);
#pragma unroll
            for (int m = 0; m < 4; ++m) {
                int r = wr + m * 16 + (lane & 15);
                afr[m] = *(const bf16x8*)(lsa + r * 128 + (kb ^ ((r & 7) << 4)));
                int rn = wc + m * 16 + (lane & 15);
                bfr[m] = *(const bf16x8*)(lsb + rn * 128 + (kb ^ ((rn & 7) << 4)));
            }
#pragma unroll
            for (int m = 0; m < 4; ++m)
#pragma unroll
                for (int n = 0; n < 4; ++n)
                    acc[m][n] = __builtin_amdgcn_mfma_f32_16x16x32_bf16(
                        afr[m], bfr[n], acc[m][n], 0, 0, 0);
        }
        __syncthreads();
    }

    float bv[4];
#pragma unroll
    for (int n = 0; n < 4; ++n) bv[n] = bias[bn + wc + n * 16 + (lane & 15)];
#pragma unroll
    for (int m = 0; m < 4; ++m)
#pragma unroll
        for (int n = 0; n < 4; ++n)
#pragma unroll
            for (int j = 0; j < 4; ++j) {
                int row = bm + wr + m * 16 + (lane >> 4) * 4 + j;
                int col = bn + wc + n * 16 + (lane & 15);
                C[(size_t)row * Nn + col] = acc[m][n][j] + bv[n];
            }
}

// ---------------------------------------------------------------------------
// fp32 GEMM for the indexer projections (kept EXACT fp32 so top-k selection
// matches the reference).  128x64 tile -> 512 blocks (vs 128 before).
// Virtual N=512: cols [0,256) = qI (wq_i,bq_i), [256,512) = kI.
// ---------------------------------------------------------------------------
__global__ __launch_bounds__(256) void gemm_qiki64(
    const float* __restrict__ x,
    const float* __restrict__ wq, const float* __restrict__ bq,
    const float* __restrict__ wk, const float* __restrict__ bk,
    float* __restrict__ qI, float* __restrict__ kI)
{
    __shared__ float la[32][LDT];
    __shared__ float lb[32][68];
    const int tid = threadIdx.x;
    const int tx = tid & 15, ty = tid >> 4;
    const int bm = blockIdx.y * 128;
    int bn = blockIdx.x * 64;
    const float* W; const float* bias; float* Out;
    if (bn < 256) { W = wq; bias = bq; Out = qI; }
    else          { W = wk; bias = bk; Out = kI; bn -= 256; }

    float acc[8][4];
#pragma unroll
    for (int i = 0; i < 8; ++i)
#pragma unroll
        for (int j = 0; j < 4; ++j) acc[i][j] = 0.0f;

    for (int k0 = 0; k0 < D_; k0 += 32) {
#pragma unroll
        for (int i = 0; i < 4; ++i) {
            int f4 = tid + (i << 8);
            int r = f4 >> 3, cq = f4 & 7;
            float4 a = *(const float4*)(x + (size_t)(bm + r) * D_ + k0 + (cq << 2));
            la[cq * 4 + 0][r] = a.x;
            la[cq * 4 + 1][r] = a.y;
            la[cq * 4 + 2][r] = a.z;
            la[cq * 4 + 3][r] = a.w;
        }
#pragma unroll
        for (int i = 0; i < 2; ++i) {
            int f4 = tid + (i << 8);
            int r = f4 >> 3, cq = f4 & 7;
            float4 w4 = *(const float4*)(W + (size_t)(bn + r) * D_ + k0 + (cq << 2));
            lb[cq * 4 + 0][r] = w4.x;
            lb[cq * 4 + 1][r] = w4.y;
            lb[cq * 4 + 2][r] = w4.z;
            lb[cq * 4 + 3][r] = w4.w;
        }
        __syncthreads();
#pragma unroll
        for (int kk = 0; kk < 32; ++kk) {
            float4 a0 = *(const float4*)&la[kk][ty * 8];
            float4 a1 = *(const float4*)&la[kk][ty * 8 + 4];
            float4 b0 = *(const float4*)&lb[kk][tx * 4];
            float av[8] = {a0.x, a0.y, a0.z, a0.w, a1.x, a1.y, a1.z, a1.w};
            float bv4[4] = {b0.x, b0.y, b0.z, b0.w};
#pragma unroll
            for (int i = 0; i < 8; ++i)
#pragma unroll
                for (int j = 0; j < 4; ++j)
                    acc[i][j] = fmaf(av[i], bv4[j], acc[i][j]);
        }
        __syncthreads();
    }

    float bs[4];
    {
        float4 q0 = *(const float4*)(bias + bn + tx * 4);
        bs[0] = q0.x; bs[1] = q0.y; bs[2] = q0.z; bs[3] = q0.w;
    }
#pragma unroll
    for (int i = 0; i < 8; ++i) {
        int rr = bm + ty * 8 + i;
        float4 o;
        o.x = acc[i][0] + bs[0];
        o.y = acc[i][1] + bs[1];
        o.z = acc[i][2] + bs[2];
        o.w = acc[i][3] + bs[3];
        *(float4*)(Out + (size_t)rr * (IH_ * ID_) + bn + tx * 4) = o;
    }
}

// ---------------------------------------------------------------------------
// Indexer scores (exact fp32): scores[b][t][s] = sum_h w_head[h]*relu(qI.kI)
// ---------------------------------------------------------------------------
__global__ __launch_bounds__(256) void scores_kernel(
    const float* __restrict__ qI, const float* __restrict__ kI,
    const float* __restrict__ w_head, float* __restrict__ scores)
{
    const int is = blockIdx.x, it = blockIdx.y, b = blockIdx.z;
    if (is > it) return;
    __shared__ float lq[32][LDT];
    __shared__ float lk[32][LDT];
    const int tid = threadIdx.x;
    const int tx = tid & 15, ty = tid >> 4;
    const int t0 = it * 128, s0 = is * 128;

    float sc[8][8];
#pragma unroll
    for (int i = 0; i < 8; ++i)
#pragma unroll
        for (int j = 0; j < 8; ++j) sc[i][j] = 0.0f;

    for (int h = 0; h < IH_; ++h) {
        float rel[8][8];
#pragma unroll
        for (int i = 0; i < 8; ++i)
#pragma unroll
            for (int j = 0; j < 8; ++j) rel[i][j] = 0.0f;

        for (int k0 = 0; k0 < ID_; k0 += 32) {
#pragma unroll
            for (int i = 0; i < 4; ++i) {
                int f4 = tid + (i << 8);
                int r = f4 >> 3;
                int cq = f4 & 7;
                float4 a = *(const float4*)(qI + (size_t)(b * T_ + t0 + r) * (IH_ * ID_) + h * ID_ + k0 + (cq << 2));
                lq[cq * 4 + 0][r] = a.x;
                lq[cq * 4 + 1][r] = a.y;
                lq[cq * 4 + 2][r] = a.z;
                lq[cq * 4 + 3][r] = a.w;
                float4 c = *(const float4*)(kI + (size_t)(b * T_ + s0 + r) * (IH_ * ID_) + h * ID_ + k0 + (cq << 2));
                lk[cq * 4 + 0][r] = c.x;
                lk[cq * 4 + 1][r] = c.y;
                lk[cq * 4 + 2][r] = c.z;
                lk[cq * 4 + 3][r] = c.w;
            }
            __syncthreads();
#pragma unroll
            for (int kk = 0; kk < 32; ++kk) {
                float4 a0 = *(const float4*)&lq[kk][ty * 8];
                float4 a1 = *(const float4*)&lq[kk][ty * 8 + 4];
                float4 b0 = *(const float4*)&lk[kk][tx * 8];
                float4 b1 = *(const float4*)&lk[kk][tx * 8 + 4];
                float av[8] = {a0.x, a0.y, a0.z, a0.w, a1.x, a1.y, a1.z, a1.w};
                float bv[8] = {b0.x, b0.y, b0.z, b0.w, b1.x, b1.y, b1.z, b1.w};
#pragma unroll
                for (int i = 0; i < 8; ++i)
#pragma unroll
                    for (int j = 0; j < 8; ++j)
                        rel[i][j] = fmaf(av[i], bv[j], rel[i][j]);
            }
            __syncthreads();
        }
        float wh = w_head[h];
#pragma unroll
        for (int i = 0; i < 8; ++i)
#pragma unroll
            for (int j = 0; j < 8; ++j)
                sc[i][j] += wh * fmaxf(rel[i][j], 0.0f);
    }

#pragma unroll
    for (int i = 0; i < 8; ++i) {
        int tt = t0 + ty * 8 + i;
        float* sp = scores + ((size_t)b * T_ + tt) * T_ + s0 + tx * 8;
        float4 o0 = {sc[i][0], sc[i][1], sc[i][2], sc[i][3]};
        float4 o1 = {sc[i][4], sc[i][5], sc[i][6], sc[i][7]};
        *(float4*)sp = o0;
        *(float4*)(sp + 4) = o1;
    }
}

// ---------------------------------------------------------------------------
// Top-64 per causal row, 1 barrier per round.  Invalidation is thread-local:
// vals[s] is only ever read by thread (s & 255), so no extra barrier needed.
// Tie-break: smaller index (matches jax.lax.top_k).
// ---------------------------------------------------------------------------
__global__ __launch_bounds__(256) void topk_kernel(
    const float* __restrict__ scores, int* __restrict__ idx_out,
    float* __restrict__ rout_out)
{
    const int row = blockIdx.x;
    const int b = row >> 11;
    const int t = row & (T_ - 1);
    const int tid = threadIdx.x;
    const int lane = tid & 63, wv = tid >> 6;
    const int n = t + 1;
    const int nv = n < K_ ? n : K_;

    __shared__ float vals[T_];
    __shared__ float rv[2][4];
    __shared__ int ri[2][4];

    const float* srow = scores + ((size_t)b * T_ + t) * T_;
    for (int s = tid; s < n; s += 256) vals[s] = srow[s];
    __syncthreads();

    int cur = 0;
    for (int r = 0; r < nv; ++r) {
        float bv = -INFINITY;
        int bi = 0x7fffffff;
        for (int s = tid; s < n; s += 256) {
            float v = vals[s];
            if (v > bv) { bv = v; bi = s; }
        }
#pragma unroll
        for (int off = 32; off; off >>= 1) {
            float v2 = __shfl_down(bv, off);
            int i2 = __shfl_down(bi, off);
            if (v2 > bv || (v2 == bv && i2 < bi)) { bv = v2; bi = i2; }
        }
        if (lane == 0) { rv[cur][wv] = bv; ri[cur][wv] = bi; }
        __syncthreads();
        float fbv = rv[cur][0];
        int fbi = ri[cur][0];
#pragma unroll
        for (int w2 = 1; w2 < 4; ++w2) {
            float v2 = rv[cur][w2];
            int i2 = ri[cur][w2];
            if (v2 > fbv || (v2 == fbv && i2 < fbi)) { fbv = v2; fbi = i2; }
        }
        if (tid == (fbi & 255)) vals[fbi] = -INFINITY;   // only this thread reads it
        if (tid == 0) {
            idx_out[(size_t)row * K_ + r] = fbi;
            rout_out[(size_t)row * K_ + r] = fbv;
        }
        cur ^= 1;
    }
    for (int r = nv + tid; r < K_; r += 256) {
        idx_out[(size_t)row * K_ + r] = 0;
        rout_out[(size_t)row * K_ + r] = 0.0f;
    }
}

// ---------------------------------------------------------------------------
// Sparse attention; writes output directly as split-bf16 (hi,lo) for the
// final MFMA GEMM.
// ---------------------------------------------------------------------------
__global__ __launch_bounds__(256) void attn_kernel(
    const float* __restrict__ qkv, const int* __restrict__ idx,
    const float* __restrict__ routing,
    unsigned short* __restrict__ atthi, unsigned short* __restrict__ attlo)
{
    const int row = blockIdx.x;
    const int b = row >> 11;
    const int t = row & (T_ - 1);
    const int tid = threadIdx.x;
    const int lane = tid & 63;
    const int wave = tid >> 6;
    const int nv = (t + 1) < K_ ? (t + 1) : K_;

    __shared__ float qs[D_];
    for (int i = tid; i < D_; i += 256) qs[i] = qkv[(size_t)row * NQKV + i];

    int myidx = 0;
    float myrout = 0.0f;
    if (lane < nv) {
        myidx = idx[(size_t)row * K_ + lane];
        myrout = routing[(size_t)row * K_ + lane];
    }
    __syncthreads();

    const float scale = 0.125f;
#pragma unroll
    for (int hh = 0; hh < 3; ++hh) {
        const int h = wave + hh * 4;
        float att = -INFINITY;
        if (lane < nv) {
            const float* kp = qkv + (size_t)(b * T_ + myidx) * NQKV + D_ + h * DH_;
            const float* qp = qs + h * DH_;
            float acc = 0.0f;
#pragma unroll
            for (int d4 = 0; d4 < 16; ++d4) {
                float4 kv4 = *(const float4*)(kp + d4 * 4);
                float4 q4 = *(const float4*)(qp + d4 * 4);
                acc = fmaf(kv4.x, q4.x, acc);
                acc = fmaf(kv4.y, q4.y, acc);
                acc = fmaf(kv4.z, q4.z, acc);
                acc = fmaf(kv4.w, q4.w, acc);
            }
            att = acc * scale;
        }
        float m = att;
#pragma unroll
        for (int off = 32; off; off >>= 1) m = fmaxf(m, __shfl_xor(m, off));
        float e = (lane < nv) ? __expf(att - m) : 0.0f;
        float ssum = e;
#pragma unroll
        for (int off = 32; off; off >>= 1) ssum += __shfl_xor(ssum, off);
        float p = e / ssum * myrout;

        float acc = 0.0f;
        for (int k = 0; k < nv; ++k) {
            float pk = __shfl(p, k);
            int ik = __shfl(myidx, k);
            acc = fmaf(pk, qkv[(size_t)(b * T_ + ik) * NQKV + 2 * D_ + h * DH_ + lane], acc);
        }
        unsigned short h16, l16;
        split2(acc, h16, l16);
        atthi[(size_t)row * D_ + h * DH_ + lane] = h16;
        attlo[(size_t)row * D_ + h * DH_ + lane] = l16;
    }
}

// ---------------------------------------------------------------------------
extern "C" void kernel_launch(void* const* d_in, const int* in_sizes, int n_in,
                              void* d_out, int out_size, void* d_ws, size_t ws_size,
                              hipStream_t stream)
{
    const float* x      = (const float*)d_in[0];
    const float* wq_i   = (const float*)d_in[1];
    const float* bq_i   = (const float*)d_in[2];
    const float* wk_i   = (const float*)d_in[3];
    const float* bk_i   = (const float*)d_in[4];
    const float* w_head = (const float*)d_in[5];
    const float* w_qkv  = (const float*)d_in[6];
    const float* b_qkv  = (const float*)d_in[7];
    const float* w_out  = (const float*)d_in[8];
    const float* b_out  = (const float*)d_in[9];
    float* out = (float*)d_out;

    // Workspace layout (94,371,840 B total — same footprint as the proven R1
    // layout).  Lifetime-disjoint aliases:
    //   wqh/wql live in the scores region (dead before scores_kernel writes)
    //   woh/wol live in the scores region (written after topk consumed scores)
    //   atthi/attlo alias xhi/xlo (x splits dead after the qkv GEMM)
    char* w = (char*)d_ws;
    float* scoresb        = (float*)w;                         // 33,554,432 B
    unsigned short* wqh   = (unsigned short*)w;                //  3,538,944 B (alias)
    unsigned short* wql   = (unsigned short*)(w + 4194304);    //  (alias)
    unsigned short* woh   = (unsigned short*)(w + 8388608);    //  1,179,648 B (alias)
    unsigned short* wol   = (unsigned short*)(w + 12582912);   //  (alias)
    float* qkv            = (float*)(w + 33554432);            // 37,748,736 B
    float* qI             = (float*)(w + 71303168);            //  4,194,304 B
    float* kI             = (float*)(w + 75497472);            //  4,194,304 B
    float* routing        = (float*)(w + 79691776);            //  1,048,576 B
    int*   idxb           = (int*)  (w + 80740352);            //  1,048,576 B
    unsigned short* xhi   = (unsigned short*)(w + 81788928);   //  6,291,456 B
    unsigned short* xlo   = (unsigned short*)(w + 88080384);   //  6,291,456 B
    unsigned short* atthi = xhi;                               //  (alias)
    unsigned short* attlo = xlo;                               //  (alias)

    dim3 blk(256);

    // split x and w_qkv into bf16 hi/lo
    split_kernel<<<dim3((M_ * D_ / 4 + 255) / 256), blk, 0, stream>>>(x, xhi, xlo, M_ * D_ / 4);
    split_kernel<<<dim3((NQKV * D_ / 4 + 255) / 256), blk, 0, stream>>>(w_qkv, wqh, wql, NQKV * D_ / 4);

    // qkv projection (MFMA)
    gemm_bf16split<<<dim3(NQKV / 128, M_ / 128), blk, 0, stream>>>(xhi, xlo, wqh, wql, b_qkv, qkv, NQKV);

    // indexer projections (exact fp32)
    gemm_qiki64<<<dim3(8, M_ / 128), blk, 0, stream>>>(x, wq_i, bq_i, wk_i, bk_i, qI, kI);

    // indexer scores + top-64
    scores_kernel<<<dim3(T_ / 128, T_ / 128, B_), blk, 0, stream>>>(qI, kI, w_head, scoresb);
    topk_kernel<<<dim3(M_), blk, 0, stream>>>(scoresb, idxb, routing);

    // w_out split (scores region is dead now)
    split_kernel<<<dim3((D_ * D_ / 4 + 255) / 256), blk, 0, stream>>>(w_out, woh, wol, D_ * D_ / 4);

    // sparse attention -> split-bf16 output
    attn_kernel<<<dim3(M_), blk, 0, stream>>>(qkv, idxb, routing, atthi, attlo);

    // output projection (MFMA)
    gemm_bf16split<<<dim3(D_ / 128, M_ / 128), blk, 0, stream>>>(atthi, attlo, woh, wol, b_out, out, D_);
}

// Round 8
// 531.581 us; speedup vs baseline: 1.9341x; 1.4005x over previous
//
#include <hip/hip_runtime.h>
#include <hip/hip_bf16.h>
#include <math.h>

#define B_   2
#define T_   2048
#define D_   768
#define H_   12
#define DH_  64
#define IH_  4
#define ID_  64
#define K_   64
#define M_   (B_ * T_)        // 4096
#define NQKV 2304

#define LDT 132               // padded LDS row stride (floats)

typedef __attribute__((ext_vector_type(8))) short bf16x8;
typedef __attribute__((ext_vector_type(4))) float f32x4;

#define GLOBAL_AS __attribute__((address_space(1)))
#define LDS_AS    __attribute__((address_space(3)))

// ---------------------------------------------------------------------------
// fp32 -> (hi,lo) bf16 split.  x ~= hi + lo with ~16-17 mantissa bits kept.
// ---------------------------------------------------------------------------
__device__ __forceinline__ void split2(float f, unsigned short& h, unsigned short& l)
{
    __bf16 b = (__bf16)f;
    h = __builtin_bit_cast(unsigned short, b);
    __bf16 c = (__bf16)(f - (float)b);
    l = __builtin_bit_cast(unsigned short, c);
}

__global__ __launch_bounds__(256) void split_kernel(
    const float* __restrict__ in, unsigned short* __restrict__ hi,
    unsigned short* __restrict__ lo, int n4)
{
    int i = blockIdx.x * 256 + threadIdx.x;
    if (i >= n4) return;
    float4 v = ((const float4*)in)[i];
    ushort4 hv, lv;
    split2(v.x, hv.x, lv.x);
    split2(v.y, hv.y, lv.y);
    split2(v.z, hv.z, lv.z);
    split2(v.w, hv.w, lv.w);
    ((ushort4*)hi)[i] = hv;
    ((ushort4*)lo)[i] = lv;
}

// ---------------------------------------------------------------------------
// Split-bf16 MFMA GEMM:  C[M,Nn] = A @ W^T + bias   (A = Ahi+Alo, W = Whi+Wlo)
// Computes Ahi*Whi + Ahi*Wlo + Alo*Whi via 36 K-tiles of 64 (3 phases x 768).
// 128x128 tile, 4 waves (each 64x64 = 4x4 frags of 16x16x32 bf16 MFMA).
// global_load_lds width 16 with pre-swizzled global source; XOR-swizzled
// LDS reads (byte ^= (row&7)<<4) kill the stride-128B bank conflict.
// ---------------------------------------------------------------------------
__global__ __launch_bounds__(256) void gemm_bf16split(
    const unsigned short* __restrict__ Ahi, const unsigned short* __restrict__ Alo,
    const unsigned short* __restrict__ Whi, const unsigned short* __restrict__ Wlo,
    const float* __restrict__ bias, float* __restrict__ C, int Nn)
{
    __shared__ char lsa[128 * 128];
    __shared__ char lsb[128 * 128];
    const int tid = threadIdx.x;
    const int lane = tid & 63;
    const int wv = tid >> 6;
    const int bm = blockIdx.y * 128, bn = blockIdx.x * 128;
    const int wr = (wv >> 1) * 64, wc = (wv & 1) * 64;

    f32x4 acc[4][4];
    const f32x4 zero = {0.0f, 0.0f, 0.0f, 0.0f};
#pragma unroll
    for (int m = 0; m < 4; ++m)
#pragma unroll
        for (int n = 0; n < 4; ++n) acc[m][n] = zero;

    const int srow = lane >> 3;           // row within an 8-row staging call
    const int scol = (lane & 7) * 16;     // byte col within 128B row

    for (int kt = 0; kt < 36; ++kt) {
        const unsigned short* Ap;
        const unsigned short* Wp;
        int kc;
        if (kt < 12)      { Ap = Ahi; Wp = Whi; kc = kt * 64; }
        else if (kt < 24) { Ap = Ahi; Wp = Wlo; kc = (kt - 12) * 64; }
        else              { Ap = Alo; Wp = Whi; kc = (kt - 24) * 64; }

#pragma unroll
        for (int i = 0; i < 4; ++i) {
            int rl = wv * 32 + i * 8 + srow;               // local row 0..127
            int sb = scol ^ ((rl & 7) << 4);               // inverse-swizzled src
            const char* ga = (const char*)Ap + ((size_t)(bm + rl) * D_ + kc) * 2 + sb;
            __builtin_amdgcn_global_load_lds((GLOBAL_AS const void*)ga,
                (LDS_AS void*)(lsa + (wv * 32 + i * 8) * 128), 16, 0, 0);
            const char* gb = (const char*)Wp + ((size_t)(bn + rl) * D_ + kc) * 2 + sb;
            __builtin_amdgcn_global_load_lds((GLOBAL_AS const void*)gb,
                (LDS_AS void*)(lsb + (wv * 32 + i * 8) * 128), 16, 0, 0);
        }
        __syncthreads();

#pragma unroll
        for (int ks = 0; ks < 2; ++ks) {
            bf16x8 afr[4], bfr[4];
            const int kb = ks * 64 + ((lane >> 4) * 16);
#pragma unroll
            for (int m = 0; m < 4; ++m) {
                int r = wr + m * 16 + (lane & 15);
                afr[m] = *(const bf16x8*)(lsa + r * 128 + (kb ^ ((r & 7) << 4)));
                int rn = wc + m * 16 + (lane & 15);
                bfr[m] = *(const bf16x8*)(lsb + rn * 128 + (kb ^ ((rn & 7) << 4)));
            }
#pragma unroll
            for (int m = 0; m < 4; ++m)
#pragma unroll
                for (int n = 0; n < 4; ++n)
                    acc[m][n] = __builtin_amdgcn_mfma_f32_16x16x32_bf16(
                        afr[m], bfr[n], acc[m][n], 0, 0, 0);
        }
        __syncthreads();
    }

    float bv[4];
#pragma unroll
    for (int n = 0; n < 4; ++n) bv[n] = bias[bn + wc + n * 16 + (lane & 15)];
#pragma unroll
    for (int m = 0; m < 4; ++m)
#pragma unroll
        for (int n = 0; n < 4; ++n)
#pragma unroll
            for (int j = 0; j < 4; ++j) {
                int row = bm + wr + m * 16 + (lane >> 4) * 4 + j;
                int col = bn + wc + n * 16 + (lane & 15);
                C[(size_t)row * Nn + col] = acc[m][n][j] + bv[n];
            }
}

// ---------------------------------------------------------------------------
// fp32 GEMM for the indexer projections (kept EXACT fp32 so top-k selection
// matches the reference).  128x64 tile -> 512 blocks.
// Virtual N=512: cols [0,256) = qI (wq_i,bq_i), [256,512) = kI.
// ---------------------------------------------------------------------------
__global__ __launch_bounds__(256) void gemm_qiki64(
    const float* __restrict__ x,
    const float* __restrict__ wq, const float* __restrict__ bq,
    const float* __restrict__ wk, const float* __restrict__ bk,
    float* __restrict__ qI, float* __restrict__ kI)
{
    __shared__ float la[32][LDT];
    __shared__ float lb[32][68];
    const int tid = threadIdx.x;
    const int tx = tid & 15, ty = tid >> 4;
    const int bm = blockIdx.y * 128;
    int bn = blockIdx.x * 64;
    const float* W; const float* bias; float* Out;
    if (bn < 256) { W = wq; bias = bq; Out = qI; }
    else          { W = wk; bias = bk; Out = kI; bn -= 256; }

    float acc[8][4];
#pragma unroll
    for (int i = 0; i < 8; ++i)
#pragma unroll
        for (int j = 0; j < 4; ++j) acc[i][j] = 0.0f;

    for (int k0 = 0; k0 < D_; k0 += 32) {
#pragma unroll
        for (int i = 0; i < 4; ++i) {
            int f4 = tid + (i << 8);
            int r = f4 >> 3, cq = f4 & 7;
            float4 a = *(const float4*)(x + (size_t)(bm + r) * D_ + k0 + (cq << 2));
            la[cq * 4 + 0][r] = a.x;
            la[cq * 4 + 1][r] = a.y;
            la[cq * 4 + 2][r] = a.z;
            la[cq * 4 + 3][r] = a.w;
        }
#pragma unroll
        for (int i = 0; i < 2; ++i) {
            int f4 = tid + (i << 8);
            int r = f4 >> 3, cq = f4 & 7;
            float4 w4 = *(const float4*)(W + (size_t)(bn + r) * D_ + k0 + (cq << 2));
            lb[cq * 4 + 0][r] = w4.x;
            lb[cq * 4 + 1][r] = w4.y;
            lb[cq * 4 + 2][r] = w4.z;
            lb[cq * 4 + 3][r] = w4.w;
        }
        __syncthreads();
#pragma unroll
        for (int kk = 0; kk < 32; ++kk) {
            float4 a0 = *(const float4*)&la[kk][ty * 8];
            float4 a1 = *(const float4*)&la[kk][ty * 8 + 4];
            float4 b0 = *(const float4*)&lb[kk][tx * 4];
            float av[8] = {a0.x, a0.y, a0.z, a0.w, a1.x, a1.y, a1.z, a1.w};
            float bv4[4] = {b0.x, b0.y, b0.z, b0.w};
#pragma unroll
            for (int i = 0; i < 8; ++i)
#pragma unroll
                for (int j = 0; j < 4; ++j)
                    acc[i][j] = fmaf(av[i], bv4[j], acc[i][j]);
        }
        __syncthreads();
    }

    float bs[4];
    {
        float4 q0 = *(const float4*)(bias + bn + tx * 4);
        bs[0] = q0.x; bs[1] = q0.y; bs[2] = q0.z; bs[3] = q0.w;
    }
#pragma unroll
    for (int i = 0; i < 8; ++i) {
        int rr = bm + ty * 8 + i;
        float4 o;
        o.x = acc[i][0] + bs[0];
        o.y = acc[i][1] + bs[1];
        o.z = acc[i][2] + bs[2];
        o.w = acc[i][3] + bs[3];
        *(float4*)(Out + (size_t)rr * (IH_ * ID_) + bn + tx * 4) = o;
    }
}

// ---------------------------------------------------------------------------
// Indexer scores (exact fp32): scores[b][t][s] = sum_h w_head[h]*relu(qI.kI)
// ---------------------------------------------------------------------------
__global__ __launch_bounds__(256) void scores_kernel(
    const float* __restrict__ qI, const float* __restrict__ kI,
    const float* __restrict__ w_head, float* __restrict__ scores)
{
    const int is = blockIdx.x, it = blockIdx.y, b = blockIdx.z;
    if (is > it) return;
    __shared__ float lq[32][LDT];
    __shared__ float lk[32][LDT];
    const int tid = threadIdx.x;
    const int tx = tid & 15, ty = tid >> 4;
    const int t0 = it * 128, s0 = is * 128;

    float sc[8][8];
#pragma unroll
    for (int i = 0; i < 8; ++i)
#pragma unroll
        for (int j = 0; j < 8; ++j) sc[i][j] = 0.0f;

    for (int h = 0; h < IH_; ++h) {
        float rel[8][8];
#pragma unroll
        for (int i = 0; i < 8; ++i)
#pragma unroll
            for (int j = 0; j < 8; ++j) rel[i][j] = 0.0f;

        for (int k0 = 0; k0 < ID_; k0 += 32) {
#pragma unroll
            for (int i = 0; i < 4; ++i) {
                int f4 = tid + (i << 8);
                int r = f4 >> 3;
                int cq = f4 & 7;
                float4 a = *(const float4*)(qI + (size_t)(b * T_ + t0 + r) * (IH_ * ID_) + h * ID_ + k0 + (cq << 2));
                lq[cq * 4 + 0][r] = a.x;
                lq[cq * 4 + 1][r] = a.y;
                lq[cq * 4 + 2][r] = a.z;
                lq[cq * 4 + 3][r] = a.w;
                float4 c = *(const float4*)(kI + (size_t)(b * T_ + s0 + r) * (IH_ * ID_) + h * ID_ + k0 + (cq << 2));
                lk[cq * 4 + 0][r] = c.x;
                lk[cq * 4 + 1][r] = c.y;
                lk[cq * 4 + 2][r] = c.z;
                lk[cq * 4 + 3][r] = c.w;
            }
            __syncthreads();
#pragma unroll
            for (int kk = 0; kk < 32; ++kk) {
                float4 a0 = *(const float4*)&lq[kk][ty * 8];
                float4 a1 = *(const float4*)&lq[kk][ty * 8 + 4];
                float4 b0 = *(const float4*)&lk[kk][tx * 8];
                float4 b1 = *(const float4*)&lk[kk][tx * 8 + 4];
                float av[8] = {a0.x, a0.y, a0.z, a0.w, a1.x, a1.y, a1.z, a1.w};
                float bv[8] = {b0.x, b0.y, b0.z, b0.w, b1.x, b1.y, b1.z, b1.w};
#pragma unroll
                for (int i = 0; i < 8; ++i)
#pragma unroll
                    for (int j = 0; j < 8; ++j)
                        rel[i][j] = fmaf(av[i], bv[j], rel[i][j]);
            }
            __syncthreads();
        }
        float wh = w_head[h];
#pragma unroll
        for (int i = 0; i < 8; ++i)
#pragma unroll
            for (int j = 0; j < 8; ++j)
                sc[i][j] += wh * fmaxf(rel[i][j], 0.0f);
    }

#pragma unroll
    for (int i = 0; i < 8; ++i) {
        int tt = t0 + ty * 8 + i;
        float* sp = scores + ((size_t)b * T_ + tt) * T_ + s0 + tx * 8;
        float4 o0 = {sc[i][0], sc[i][1], sc[i][2], sc[i][3]};
        float4 o1 = {sc[i][4], sc[i][5], sc[i][6], sc[i][7]};
        *(float4*)sp = o0;
        *(float4*)(sp + 4) = o1;
    }
}

// ---------------------------------------------------------------------------
// Top-64 per causal row via 4-pass 8-bit RADIX SELECT (replaces 64-round
// serial extraction: ~20 barriers instead of 128, ~6 linear scans not 64).
// Keys are order-preserving uint transforms of fp32; tie-break at the
// threshold value takes ascending index (matches jax.lax.top_k).  Output
// order within the K slots is arbitrary — downstream attn is permutation-
// invariant in k (softmax + routing + PV all per-slot).
// ---------------------------------------------------------------------------
__global__ __launch_bounds__(256) void topk_kernel(
    const float* __restrict__ scores, int* __restrict__ idx_out,
    float* __restrict__ rout_out)
{
    const int row = blockIdx.x;
    const int b = row >> 11;
    const int t = row & (T_ - 1);
    const int tid = threadIdx.x;
    const int lane = tid & 63;
    const int wv = tid >> 6;
    const int n = t + 1;
    const float* srow = scores + ((size_t)b * T_ + t) * T_;
    const size_t obase = (size_t)row * K_;

    if (n <= K_) {                       // t < 64: everything is selected
        for (int r = tid; r < K_; r += 256) {
            idx_out[obase + r] = (r < n) ? r : 0;
            rout_out[obase + r] = (r < n) ? srow[r] : 0.0f;
        }
        return;
    }

    __shared__ unsigned int keys[T_];
    __shared__ unsigned int hist[256];
    __shared__ unsigned int nb[256];
    __shared__ int wt0[4], wt1[4];
    __shared__ unsigned int sh_prefix;
    __shared__ int sh_need;

    for (int s = tid; s < n; s += 256) {
        unsigned int u = __float_as_uint(srow[s]);
        u ^= (u & 0x80000000u) ? 0xffffffffu : 0x80000000u;  // order-preserving
        keys[s] = u;
    }

    unsigned int prefix = 0;
    int need = K_;
    for (int pass = 0; pass < 4; ++pass) {
        const int shift = 24 - pass * 8;
        const unsigned int pmask = (pass == 0) ? 0u : (0xffffffffu << (shift + 8));
        hist[tid] = 0;
        __syncthreads();                 // keys ready (pass 0) + hist zeroed
        for (int s = tid; s < n; s += 256) {
            unsigned int k = keys[s];
            if ((k & pmask) == prefix)
                atomicAdd(&hist[(k >> shift) & 0xffu], 1u);
        }
        __syncthreads();
        // inclusive suffix scan of hist via wave shuffles + wave totals
        int v = (int)hist[tid];
#pragma unroll
        for (int off = 1; off < 64; off <<= 1) {
            int o = __shfl_down(v, off);
            if (lane + off < 64) v += o;
        }
        if (lane == 0) wt0[wv] = v;
        __syncthreads();
        int wadd = 0;
#pragma unroll
        for (int w2 = 0; w2 < 4; ++w2) if (w2 > wv) wadd += wt0[w2];
        int sfx = v + wadd;              // count of candidates with byte >= tid
        nb[tid] = (unsigned)sfx;
        __syncthreads();
        int sfx1 = (tid < 255) ? (int)nb[tid + 1] : 0;
        if (sfx >= need && sfx1 < need) {        // unique crossing bucket
            sh_prefix = prefix | ((unsigned)tid << shift);
            sh_need = need - sfx1;
        }
        __syncthreads();
        prefix = sh_prefix;
        need = sh_need;
        __syncthreads();
    }
    const unsigned int thr = prefix;     // exact 32-bit K-th largest key

    // blocked collection: contiguous chunk per thread => equal-key ranks are
    // ascending-global-index (jax tie-break)
    const int chunk = (n + 255) >> 8;
    const int base = tid * chunk;
    int cg = 0, ce = 0;
    for (int j = 0; j < chunk; ++j) {
        int s = base + j;
        if (s < n) {
            unsigned int k = keys[s];
            cg += (k > thr);
            ce += (k == thr);
        }
    }
    int vg = cg, ve = ce;                // inclusive prefix scans over threads
#pragma unroll
    for (int off = 1; off < 64; off <<= 1) {
        int og = __shfl_up(vg, off);
        int oe = __shfl_up(ve, off);
        if (lane >= off) { vg += og; ve += oe; }
    }
    if (lane == 63) { wt0[wv] = vg; wt1[wv] = ve; }
    __syncthreads();
    int offg = 0, offe = 0, G = 0;
#pragma unroll
    for (int w2 = 0; w2 < 4; ++w2) {
        G += wt0[w2];
        if (w2 < wv) { offg += wt0[w2]; offe += wt1[w2]; }
    }
    int sg = vg + offg - cg;             // exclusive prefix (greater)
    int se = ve + offe - ce;             // exclusive prefix (equal)
    for (int j = 0; j < chunk; ++j) {
        int s = base + j;
        if (s < n) {
            unsigned int k = keys[s];
            if (k >= thr) {
                unsigned int u = k ^ ((k & 0x80000000u) ? 0x80000000u : 0xffffffffu);
                if (k > thr) {
                    idx_out[obase + sg] = s;
                    rout_out[obase + sg] = __uint_as_float(u);
                    sg++;
                } else {
                    if (se < need) {
                        idx_out[obase + G + se] = s;
                        rout_out[obase + G + se] = __uint_as_float(u);
                    }
                    se++;
                }
            }
        }
    }
}

// ---------------------------------------------------------------------------
// Sparse attention; writes output directly as split-bf16 (hi,lo) for the
// final MFMA GEMM.
// ---------------------------------------------------------------------------
__global__ __launch_bounds__(256) void attn_kernel(
    const float* __restrict__ qkv, const int* __restrict__ idx,
    const float* __restrict__ routing,
    unsigned short* __restrict__ atthi, unsigned short* __restrict__ attlo)
{
    const int row = blockIdx.x;
    const int b = row >> 11;
    const int t = row & (T_ - 1);
    const int tid = threadIdx.x;
    const int lane = tid & 63;
    const int wave = tid >> 6;
    const int nv = (t + 1) < K_ ? (t + 1) : K_;

    __shared__ float qs[D_];
    for (int i = tid; i < D_; i += 256) qs[i] = qkv[(size_t)row * NQKV + i];

    int myidx = 0;
    float myrout = 0.0f;
    if (lane < nv) {
        myidx = idx[(size_t)row * K_ + lane];
        myrout = routing[(size_t)row * K_ + lane];
    }
    __syncthreads();

    const float scale = 0.125f;
#pragma unroll
    for (int hh = 0; hh < 3; ++hh) {
        const int h = wave + hh * 4;
        float att = -INFINITY;
        if (lane < nv) {
            const float* kp = qkv + (size_t)(b * T_ + myidx) * NQKV + D_ + h * DH_;
            const float* qp = qs + h * DH_;
            float acc = 0.0f;
#pragma unroll
            for (int d4 = 0; d4 < 16; ++d4) {
                float4 kv4 = *(const float4*)(kp + d4 * 4);
                float4 q4 = *(const float4*)(qp + d4 * 4);
                acc = fmaf(kv4.x, q4.x, acc);
                acc = fmaf(kv4.y, q4.y, acc);
                acc = fmaf(kv4.z, q4.z, acc);
                acc = fmaf(kv4.w, q4.w, acc);
            }
            att = acc * scale;
        }
        float m = att;
#pragma unroll
        for (int off = 32; off; off >>= 1) m = fmaxf(m, __shfl_xor(m, off));
        float e = (lane < nv) ? __expf(att - m) : 0.0f;
        float ssum = e;
#pragma unroll
        for (int off = 32; off; off >>= 1) ssum += __shfl_xor(ssum, off);
        float p = e / ssum * myrout;

        float acc = 0.0f;
        for (int k = 0; k < nv; ++k) {
            float pk = __shfl(p, k);
            int ik = __shfl(myidx, k);
            acc = fmaf(pk, qkv[(size_t)(b * T_ + ik) * NQKV + 2 * D_ + h * DH_ + lane], acc);
        }
        unsigned short h16, l16;
        split2(acc, h16, l16);
        atthi[(size_t)row * D_ + h * DH_ + lane] = h16;
        attlo[(size_t)row * D_ + h * DH_ + lane] = l16;
    }
}

// ---------------------------------------------------------------------------
extern "C" void kernel_launch(void* const* d_in, const int* in_sizes, int n_in,
                              void* d_out, int out_size, void* d_ws, size_t ws_size,
                              hipStream_t stream)
{
    const float* x      = (const float*)d_in[0];
    const float* wq_i   = (const float*)d_in[1];
    const float* bq_i   = (const float*)d_in[2];
    const float* wk_i   = (const float*)d_in[3];
    const float* bk_i   = (const float*)d_in[4];
    const float* w_head = (const float*)d_in[5];
    const float* w_qkv  = (const float*)d_in[6];
    const float* b_qkv  = (const float*)d_in[7];
    const float* w_out  = (const float*)d_in[8];
    const float* b_out  = (const float*)d_in[9];
    float* out = (float*)d_out;

    // Workspace layout (94,371,840 B total).  Lifetime-disjoint aliases:
    //   wqh/wql live in the scores region (dead before scores_kernel writes)
    //   woh/wol live in the scores region (written after topk consumed scores)
    //   atthi/attlo alias xhi/xlo (x splits dead after the qkv GEMM)
    char* w = (char*)d_ws;
    float* scoresb        = (float*)w;                         // 33,554,432 B
    unsigned short* wqh   = (unsigned short*)w;                //  3,538,944 B (alias)
    unsigned short* wql   = (unsigned short*)(w + 4194304);    //  (alias)
    unsigned short* woh   = (unsigned short*)(w + 8388608);    //  1,179,648 B (alias)
    unsigned short* wol   = (unsigned short*)(w + 12582912);   //  (alias)
    float* qkv            = (float*)(w + 33554432);            // 37,748,736 B
    float* qI             = (float*)(w + 71303168);            //  4,194,304 B
    float* kI             = (float*)(w + 75497472);            //  4,194,304 B
    float* routing        = (float*)(w + 79691776);            //  1,048,576 B
    int*   idxb           = (int*)  (w + 80740352);            //  1,048,576 B
    unsigned short* xhi   = (unsigned short*)(w + 81788928);   //  6,291,456 B
    unsigned short* xlo   = (unsigned short*)(w + 88080384);   //  6,291,456 B
    unsigned short* atthi = xhi;                               //  (alias)
    unsigned short* attlo = xlo;                               //  (alias)

    dim3 blk(256);

    // split x and w_qkv into bf16 hi/lo
    split_kernel<<<dim3((M_ * D_ / 4 + 255) / 256), blk, 0, stream>>>(x, xhi, xlo, M_ * D_ / 4);
    split_kernel<<<dim3((NQKV * D_ / 4 + 255) / 256), blk, 0, stream>>>(w_qkv, wqh, wql, NQKV * D_ / 4);

    // qkv projection (MFMA)
    gemm_bf16split<<<dim3(NQKV / 128, M_ / 128), blk, 0, stream>>>(xhi, xlo, wqh, wql, b_qkv, qkv, NQKV);

    // indexer projections (exact fp32)
    gemm_qiki64<<<dim3(8, M_ / 128), blk, 0, stream>>>(x, wq_i, bq_i, wk_i, bk_i, qI, kI);

    // indexer scores + top-64 (radix select)
    scores_kernel<<<dim3(T_ / 128, T_ / 128, B_), blk, 0, stream>>>(qI, kI, w_head, scoresb);
    topk_kernel<<<dim3(M_), blk, 0, stream>>>(scoresb, idxb, routing);

    // w_out split (scores region is dead now)
    split_kernel<<<dim3((D_ * D_ / 4 + 255) / 256), blk, 0, stream>>>(w_out, woh, wol, D_ * D_ / 4);

    // sparse attention -> split-bf16 output
    attn_kernel<<<dim3(M_), blk, 0, stream>>>(qkv, idxb, routing, atthi, attlo);

    // output projection (MFMA)
    gemm_bf16split<<<dim3(D_ / 128, M_ / 128), blk, 0, stream>>>(atthi, attlo, woh, wol, b_out, out, D_);
}

// Round 10
// 486.315 us; speedup vs baseline: 2.1141x; 1.0931x over previous
//
#include <hip/hip_runtime.h>
#include <hip/hip_bf16.h>
#include <math.h>

#define B_   2
#define T_   2048
#define D_   768
#define H_   12
#define DH_  64
#define IH_  4
#define ID_  64
#define K_   64
#define M_   (B_ * T_)        // 4096
#define NQKV 2304

#define LDT 132               // padded LDS row stride (floats)

typedef __attribute__((ext_vector_type(8))) short bf16x8;
typedef __attribute__((ext_vector_type(4))) float f32x4;

#define GLOBAL_AS __attribute__((address_space(1)))
#define LDS_AS    __attribute__((address_space(3)))

// ---------------------------------------------------------------------------
// fp32 -> (hi,lo) bf16 split.  x ~= hi + lo with ~16-17 mantissa bits kept.
// ---------------------------------------------------------------------------
__device__ __forceinline__ void split2(float f, unsigned short& h, unsigned short& l)
{
    __bf16 b = (__bf16)f;
    h = __builtin_bit_cast(unsigned short, b);
    __bf16 c = (__bf16)(f - (float)b);
    l = __builtin_bit_cast(unsigned short, c);
}

__global__ __launch_bounds__(256) void split_kernel(
    const float* __restrict__ in, unsigned short* __restrict__ hi,
    unsigned short* __restrict__ lo, int n4)
{
    int i = blockIdx.x * 256 + threadIdx.x;
    if (i >= n4) return;
    float4 v = ((const float4*)in)[i];
    ushort4 hv, lv;
    split2(v.x, hv.x, lv.x);
    split2(v.y, hv.y, lv.y);
    split2(v.z, hv.z, lv.z);
    split2(v.w, hv.w, lv.w);
    ((ushort4*)hi)[i] = hv;
    ((ushort4*)lo)[i] = lv;
}

// ---------------------------------------------------------------------------
// Split-bf16 MFMA GEMM:  C[M,Nn] = A @ W^T + bias   (A = Ahi+Alo, W = Whi+Wlo)
// Computes Ahi*Whi + Ahi*Wlo + Alo*Whi via 36 K-tiles of 64 (3 phases x 768).
// 128x128 tile, 4 waves (each 64x64 = 4x4 frags of 16x16x32 bf16 MFMA).
// global_load_lds width 16 with pre-swizzled global source; XOR-swizzled
// LDS reads (byte ^= (row&7)<<4) kill the stride-128B bank conflict.
// ---------------------------------------------------------------------------
__global__ __launch_bounds__(256) void gemm_bf16split(
    const unsigned short* __restrict__ Ahi, const unsigned short* __restrict__ Alo,
    const unsigned short* __restrict__ Whi, const unsigned short* __restrict__ Wlo,
    const float* __restrict__ bias, float* __restrict__ C, int Nn)
{
    __shared__ char lsa[128 * 128];
    __shared__ char lsb[128 * 128];
    const int tid = threadIdx.x;
    const int lane = tid & 63;
    const int wv = tid >> 6;
    const int bm = blockIdx.y * 128, bn = blockIdx.x * 128;
    const int wr = (wv >> 1) * 64, wc = (wv & 1) * 64;

    f32x4 acc[4][4];
    const f32x4 zero = {0.0f, 0.0f, 0.0f, 0.0f};
#pragma unroll
    for (int m = 0; m < 4; ++m)
#pragma unroll
        for (int n = 0; n < 4; ++n) acc[m][n] = zero;

    const int srow = lane >> 3;           // row within an 8-row staging call
    const int scol = (lane & 7) * 16;     // byte col within 128B row

    for (int kt = 0; kt < 36; ++kt) {
        const unsigned short* Ap;
        const unsigned short* Wp;
        int kc;
        if (kt < 12)      { Ap = Ahi; Wp = Whi; kc = kt * 64; }
        else if (kt < 24) { Ap = Ahi; Wp = Wlo; kc = (kt - 12) * 64; }
        else              { Ap = Alo; Wp = Whi; kc = (kt - 24) * 64; }

#pragma unroll
        for (int i = 0; i < 4; ++i) {
            int rl = wv * 32 + i * 8 + srow;               // local row 0..127
            int sb = scol ^ ((rl & 7) << 4);               // inverse-swizzled src
            const char* ga = (const char*)Ap + ((size_t)(bm + rl) * D_ + kc) * 2 + sb;
            __builtin_amdgcn_global_load_lds((GLOBAL_AS const void*)ga,
                (LDS_AS void*)(lsa + (wv * 32 + i * 8) * 128), 16, 0, 0);
            const char* gb = (const char*)Wp + ((size_t)(bn + rl) * D_ + kc) * 2 + sb;
            __builtin_amdgcn_global_load_lds((GLOBAL_AS const void*)gb,
                (LDS_AS void*)(lsb + (wv * 32 + i * 8) * 128), 16, 0, 0);
        }
        __syncthreads();

#pragma unroll
        for (int ks = 0; ks < 2; ++ks) {
            bf16x8 afr[4], bfr[4];
            const int kb = ks * 64 + ((lane >> 4) * 16);
#pragma unroll
            for (int m = 0; m < 4; ++m) {
                int r = wr + m * 16 + (lane & 15);
                afr[m] = *(const bf16x8*)(lsa + r * 128 + (kb ^ ((r & 7) << 4)));
                int rn = wc + m * 16 + (lane & 15);
                bfr[m] = *(const bf16x8*)(lsb + rn * 128 + (kb ^ ((rn & 7) << 4)));
            }
#pragma unroll
            for (int m = 0; m < 4; ++m)
#pragma unroll
                for (int n = 0; n < 4; ++n)
                    acc[m][n] = __builtin_amdgcn_mfma_f32_16x16x32_bf16(
                        afr[m], bfr[n], acc[m][n], 0, 0, 0);
        }
        __syncthreads();
    }

    float bv[4];
#pragma unroll
    for (int n = 0; n < 4; ++n) bv[n] = bias[bn + wc + n * 16 + (lane & 15)];
#pragma unroll
    for (int m = 0; m < 4; ++m)
#pragma unroll
        for (int n = 0; n < 4; ++n)
#pragma unroll
            for (int j = 0; j < 4; ++j) {
                int row = bm + wr + m * 16 + (lane >> 4) * 4 + j;
                int col = bn + wc + n * 16 + (lane & 15);
                C[(size_t)row * Nn + col] = acc[m][n][j] + bv[n];
            }
}

// ---------------------------------------------------------------------------
// fp32 GEMM for the indexer projections (kept EXACT fp32 so top-k selection
// matches the reference).  128x64 tile -> 512 blocks.
// Virtual N=512: cols [0,256) = qI (wq_i,bq_i), [256,512) = kI.
// ---------------------------------------------------------------------------
__global__ __launch_bounds__(256) void gemm_qiki64(
    const float* __restrict__ x,
    const float* __restrict__ wq, const float* __restrict__ bq,
    const float* __restrict__ wk, const float* __restrict__ bk,
    float* __restrict__ qI, float* __restrict__ kI)
{
    __shared__ float la[32][LDT];
    __shared__ float lb[32][68];
    const int tid = threadIdx.x;
    const int tx = tid & 15, ty = tid >> 4;
    const int bm = blockIdx.y * 128;
    int bn = blockIdx.x * 64;
    const float* W; const float* bias; float* Out;
    if (bn < 256) { W = wq; bias = bq; Out = qI; }
    else          { W = wk; bias = bk; Out = kI; bn -= 256; }

    float acc[8][4];
#pragma unroll
    for (int i = 0; i < 8; ++i)
#pragma unroll
        for (int j = 0; j < 4; ++j) acc[i][j] = 0.0f;

    for (int k0 = 0; k0 < D_; k0 += 32) {
#pragma unroll
        for (int i = 0; i < 4; ++i) {
            int f4 = tid + (i << 8);
            int r = f4 >> 3, cq = f4 & 7;
            float4 a = *(const float4*)(x + (size_t)(bm + r) * D_ + k0 + (cq << 2));
            la[cq * 4 + 0][r] = a.x;
            la[cq * 4 + 1][r] = a.y;
            la[cq * 4 + 2][r] = a.z;
            la[cq * 4 + 3][r] = a.w;
        }
#pragma unroll
        for (int i = 0; i < 2; ++i) {
            int f4 = tid + (i << 8);
            int r = f4 >> 3, cq = f4 & 7;
            float4 w4 = *(const float4*)(W + (size_t)(bn + r) * D_ + k0 + (cq << 2));
            lb[cq * 4 + 0][r] = w4.x;
            lb[cq * 4 + 1][r] = w4.y;
            lb[cq * 4 + 2][r] = w4.z;
            lb[cq * 4 + 3][r] = w4.w;
        }
        __syncthreads();
#pragma unroll
        for (int kk = 0; kk < 32; ++kk) {
            float4 a0 = *(const float4*)&la[kk][ty * 8];
            float4 a1 = *(const float4*)&la[kk][ty * 8 + 4];
            float4 b0 = *(const float4*)&lb[kk][tx * 4];
            float av[8] = {a0.x, a0.y, a0.z, a0.w, a1.x, a1.y, a1.z, a1.w};
            float bv4[4] = {b0.x, b0.y, b0.z, b0.w};
#pragma unroll
            for (int i = 0; i < 8; ++i)
#pragma unroll
                for (int j = 0; j < 4; ++j)
                    acc[i][j] = fmaf(av[i], bv4[j], acc[i][j]);
        }
        __syncthreads();
    }

    float bs[4];
    {
        float4 q0 = *(const float4*)(bias + bn + tx * 4);
        bs[0] = q0.x; bs[1] = q0.y; bs[2] = q0.z; bs[3] = q0.w;
    }
#pragma unroll
    for (int i = 0; i < 8; ++i) {
        int rr = bm + ty * 8 + i;
        float4 o;
        o.x = acc[i][0] + bs[0];
        o.y = acc[i][1] + bs[1];
        o.z = acc[i][2] + bs[2];
        o.w = acc[i][3] + bs[3];
        *(float4*)(Out + (size_t)rr * (IH_ * ID_) + bn + tx * 4) = o;
    }
}

// ---------------------------------------------------------------------------
// Indexer scores (exact fp32): scores[b][t][s] = sum_h w_head[h]*relu(qI.kI)
// ---------------------------------------------------------------------------
__global__ __launch_bounds__(256) void scores_kernel(
    const float* __restrict__ qI, const float* __restrict__ kI,
    const float* __restrict__ w_head, float* __restrict__ scores)
{
    const int is = blockIdx.x, it = blockIdx.y, b = blockIdx.z;
    if (is > it) return;
    __shared__ float lq[32][LDT];
    __shared__ float lk[32][LDT];
    const int tid = threadIdx.x;
    const int tx = tid & 15, ty = tid >> 4;
    const int t0 = it * 128, s0 = is * 128;

    float sc[8][8];
#pragma unroll
    for (int i = 0; i < 8; ++i)
#pragma unroll
        for (int j = 0; j < 8; ++j) sc[i][j] = 0.0f;

    for (int h = 0; h < IH_; ++h) {
        float rel[8][8];
#pragma unroll
        for (int i = 0; i < 8; ++i)
#pragma unroll
            for (int j = 0; j < 8; ++j) rel[i][j] = 0.0f;

        for (int k0 = 0; k0 < ID_; k0 += 32) {
#pragma unroll
            for (int i = 0; i < 4; ++i) {
                int f4 = tid + (i << 8);
                int r = f4 >> 3;
                int cq = f4 & 7;
                float4 a = *(const float4*)(qI + (size_t)(b * T_ + t0 + r) * (IH_ * ID_) + h * ID_ + k0 + (cq << 2));
                lq[cq * 4 + 0][r] = a.x;
                lq[cq * 4 + 1][r] = a.y;
                lq[cq * 4 + 2][r] = a.z;
                lq[cq * 4 + 3][r] = a.w;
                float4 c = *(const float4*)(kI + (size_t)(b * T_ + s0 + r) * (IH_ * ID_) + h * ID_ + k0 + (cq << 2));
                lk[cq * 4 + 0][r] = c.x;
                lk[cq * 4 + 1][r] = c.y;
                lk[cq * 4 + 2][r] = c.z;
                lk[cq * 4 + 3][r] = c.w;
            }
            __syncthreads();
#pragma unroll
            for (int kk = 0; kk < 32; ++kk) {
                float4 a0 = *(const float4*)&lq[kk][ty * 8];
                float4 a1 = *(const float4*)&lq[kk][ty * 8 + 4];
                float4 b0 = *(const float4*)&lk[kk][tx * 8];
                float4 b1 = *(const float4*)&lk[kk][tx * 8 + 4];
                float av[8] = {a0.x, a0.y, a0.z, a0.w, a1.x, a1.y, a1.z, a1.w};
                float bv[8] = {b0.x, b0.y, b0.z, b0.w, b1.x, b1.y, b1.z, b1.w};
#pragma unroll
                for (int i = 0; i < 8; ++i)
#pragma unroll
                    for (int j = 0; j < 8; ++j)
                        rel[i][j] = fmaf(av[i], bv[j], rel[i][j]);
            }
            __syncthreads();
        }
        float wh = w_head[h];
#pragma unroll
        for (int i = 0; i < 8; ++i)
#pragma unroll
            for (int j = 0; j < 8; ++j)
                sc[i][j] += wh * fmaxf(rel[i][j], 0.0f);
    }

#pragma unroll
    for (int i = 0; i < 8; ++i) {
        int tt = t0 + ty * 8 + i;
        float* sp = scores + ((size_t)b * T_ + tt) * T_ + s0 + tx * 8;
        float4 o0 = {sc[i][0], sc[i][1], sc[i][2], sc[i][3]};
        float4 o1 = {sc[i][4], sc[i][5], sc[i][6], sc[i][7]};
        *(float4*)sp = o0;
        *(float4*)(sp + 4) = o1;
    }
}

// ---------------------------------------------------------------------------
// Top-64 per causal row via 4-pass 8-bit RADIX SELECT.
// Keys are order-preserving uint transforms of fp32; tie-break at the
// threshold value takes ascending index (matches jax.lax.top_k).
// ---------------------------------------------------------------------------
__global__ __launch_bounds__(256) void topk_kernel(
    const float* __restrict__ scores, int* __restrict__ idx_out,
    float* __restrict__ rout_out)
{
    const int row = blockIdx.x;
    const int b = row >> 11;
    const int t = row & (T_ - 1);
    const int tid = threadIdx.x;
    const int lane = tid & 63;
    const int wv = tid >> 6;
    const int n = t + 1;
    const float* srow = scores + ((size_t)b * T_ + t) * T_;
    const size_t obase = (size_t)row * K_;

    if (n <= K_) {                       // t < 64: everything is selected
        for (int r = tid; r < K_; r += 256) {
            idx_out[obase + r] = (r < n) ? r : 0;
            rout_out[obase + r] = (r < n) ? srow[r] : 0.0f;
        }
        return;
    }

    __shared__ unsigned int keys[T_];
    __shared__ unsigned int hist[256];
    __shared__ unsigned int nb[256];
    __shared__ int wt0[4], wt1[4];
    __shared__ unsigned int sh_prefix;
    __shared__ int sh_need;

    for (int s = tid; s < n; s += 256) {
        unsigned int u = __float_as_uint(srow[s]);
        u ^= (u & 0x80000000u) ? 0xffffffffu : 0x80000000u;  // order-preserving
        keys[s] = u;
    }

    unsigned int prefix = 0;
    int need = K_;
    for (int pass = 0; pass < 4; ++pass) {
        const int shift = 24 - pass * 8;
        const unsigned int pmask = (pass == 0) ? 0u : (0xffffffffu << (shift + 8));
        hist[tid] = 0;
        __syncthreads();                 // keys ready (pass 0) + hist zeroed
        for (int s = tid; s < n; s += 256) {
            unsigned int k = keys[s];
            if ((k & pmask) == prefix)
                atomicAdd(&hist[(k >> shift) & 0xffu], 1u);
        }
        __syncthreads();
        // inclusive suffix scan of hist via wave shuffles + wave totals
        int v = (int)hist[tid];
#pragma unroll
        for (int off = 1; off < 64; off <<= 1) {
            int o = __shfl_down(v, off);
            if (lane + off < 64) v += o;
        }
        if (lane == 0) wt0[wv] = v;
        __syncthreads();
        int wadd = 0;
#pragma unroll
        for (int w2 = 0; w2 < 4; ++w2) if (w2 > wv) wadd += wt0[w2];
        int sfx = v + wadd;              // count of candidates with byte >= tid
        nb[tid] = (unsigned)sfx;
        __syncthreads();
        int sfx1 = (tid < 255) ? (int)nb[tid + 1] : 0;
        if (sfx >= need && sfx1 < need) {        // unique crossing bucket
            sh_prefix = prefix | ((unsigned)tid << shift);
            sh_need = need - sfx1;
        }
        __syncthreads();
        prefix = sh_prefix;
        need = sh_need;
        __syncthreads();
    }
    const unsigned int thr = prefix;     // exact 32-bit K-th largest key

    // blocked collection: contiguous chunk per thread => equal-key ranks are
    // ascending-global-index (jax tie-break)
    const int chunk = (n + 255) >> 8;
    const int base = tid * chunk;
    int cg = 0, ce = 0;
    for (int j = 0; j < chunk; ++j) {
        int s = base + j;
        if (s < n) {
            unsigned int k = keys[s];
            cg += (k > thr);
            ce += (k == thr);
        }
    }
    int vg = cg, ve = ce;                // inclusive prefix scans over threads
#pragma unroll
    for (int off = 1; off < 64; off <<= 1) {
        int og = __shfl_up(vg, off);
        int oe = __shfl_up(ve, off);
        if (lane >= off) { vg += og; ve += oe; }
    }
    if (lane == 63) { wt0[wv] = vg; wt1[wv] = ve; }
    __syncthreads();
    int offg = 0, offe = 0, G = 0;
#pragma unroll
    for (int w2 = 0; w2 < 4; ++w2) {
        G += wt0[w2];
        if (w2 < wv) { offg += wt0[w2]; offe += wt1[w2]; }
    }
    int sg = vg + offg - cg;             // exclusive prefix (greater)
    int se = ve + offe - ce;             // exclusive prefix (equal)
    for (int j = 0; j < chunk; ++j) {
        int s = base + j;
        if (s < n) {
            unsigned int k = keys[s];
            if (k >= thr) {
                unsigned int u = k ^ ((k & 0x80000000u) ? 0x80000000u : 0xffffffffu);
                if (k > thr) {
                    idx_out[obase + sg] = s;
                    rout_out[obase + sg] = __uint_as_float(u);
                    sg++;
                } else {
                    if (se < need) {
                        idx_out[obase + G + se] = s;
                        rout_out[obase + G + se] = __uint_as_float(u);
                    }
                    se++;
                }
            }
        }
    }
}

// ---------------------------------------------------------------------------
// Sparse attention.  QK/softmax: lane = k.  PV: lane = d, p and V-row offsets
// staged in LDS (broadcast ds_read_b128, no ds_bpermute), 3 heads interleaved
// -> 3 independent fma chains with ~24 gathered loads in flight.
// Accumulation order over k is ascending (identical to prior kernel).
// Writes output as split-bf16 (hi,lo) for the final MFMA GEMM.
// ---------------------------------------------------------------------------
__global__ __launch_bounds__(256) void attn_kernel(
    const float* __restrict__ qkv, const int* __restrict__ idx,
    const float* __restrict__ routing,
    unsigned short* __restrict__ atthi, unsigned short* __restrict__ attlo)
{
    const int row = blockIdx.x;
    const int b = row >> 11;
    const int t = row & (T_ - 1);
    const int tid = threadIdx.x;
    const int lane = tid & 63;
    const int wave = tid >> 6;
    const int nv = (t + 1) < K_ ? (t + 1) : K_;

    __shared__ float qs[D_];
    __shared__ int vboff[K_];           // (b*T+idx_k)*NQKV element offsets
    __shared__ float pbuf[4][3][K_];    // per-wave, per-head routing-scaled p

    for (int i = tid; i < D_; i += 256) qs[i] = qkv[(size_t)row * NQKV + i];

    int myidx = 0;
    float myrout = 0.0f;
    if (lane < nv) {
        myidx = idx[(size_t)row * K_ + lane];
        myrout = routing[(size_t)row * K_ + lane];
    }
    if (wave == 0) vboff[lane] = (b * T_ + myidx) * NQKV;
    __syncthreads();

    const float scale = 0.125f;          // 1/sqrt(64)
#pragma unroll
    for (int hh = 0; hh < 3; ++hh) {
        const int h = wave + hh * 4;
        float att = -INFINITY;
        if (lane < nv) {
            const float* kp = qkv + (size_t)(b * T_ + myidx) * NQKV + D_ + h * DH_;
            const float* qp = qs + h * DH_;
            float acc = 0.0f;
#pragma unroll
            for (int d4 = 0; d4 < 16; ++d4) {
                float4 kv4 = *(const float4*)(kp + d4 * 4);
                float4 q4 = *(const float4*)(qp + d4 * 4);
                acc = fmaf(kv4.x, q4.x, acc);
                acc = fmaf(kv4.y, q4.y, acc);
                acc = fmaf(kv4.z, q4.z, acc);
                acc = fmaf(kv4.w, q4.w, acc);
            }
            att = acc * scale;
        }
        float m = att;
#pragma unroll
        for (int off = 32; off; off >>= 1) m = fmaxf(m, __shfl_xor(m, off));
        float e = (lane < nv) ? __expf(att - m) : 0.0f;
        float ssum = e;
#pragma unroll
        for (int off = 32; off; off >>= 1) ssum += __shfl_xor(ssum, off);
        pbuf[wave][hh][lane] = e / ssum * myrout;   // 0 for invalid lanes
    }
    __syncthreads();                     // pbuf complete before PV reads

    // PV: lane = d; heads wave, wave+4, wave+8 interleaved.
    float acc0 = 0.0f, acc1 = 0.0f, acc2 = 0.0f;
    const float* vbase = qkv + 2 * D_ + wave * DH_ + lane;   // + vboff[k]
    if (nv == K_) {
#pragma unroll
        for (int k0 = 0; k0 < K_; k0 += 8) {
            float4 pa0 = *(const float4*)&pbuf[wave][0][k0];
            float4 pa1 = *(const float4*)&pbuf[wave][0][k0 + 4];
            float4 pb0 = *(const float4*)&pbuf[wave][1][k0];
            float4 pb1 = *(const float4*)&pbuf[wave][1][k0 + 4];
            float4 pc0 = *(const float4*)&pbuf[wave][2][k0];
            float4 pc1 = *(const float4*)&pbuf[wave][2][k0 + 4];
            int4 vo0 = *(const int4*)&vboff[k0];
            int4 vo1 = *(const int4*)&vboff[k0 + 4];
            const int offs[8] = {vo0.x, vo0.y, vo0.z, vo0.w,
                                 vo1.x, vo1.y, vo1.z, vo1.w};
            const float p0[8] = {pa0.x, pa0.y, pa0.z, pa0.w,
                                 pa1.x, pa1.y, pa1.z, pa1.w};
            const float p1[8] = {pb0.x, pb0.y, pb0.z, pb0.w,
                                 pb1.x, pb1.y, pb1.z, pb1.w};
            const float p2[8] = {pc0.x, pc0.y, pc0.z, pc0.w,
                                 pc1.x, pc1.y, pc1.z, pc1.w};
#pragma unroll
            for (int j = 0; j < 8; ++j) {
                const float* vp = vbase + offs[j];
                acc0 = fmaf(p0[j], vp[0],        acc0);
                acc1 = fmaf(p1[j], vp[4 * DH_],  acc1);   // +1024 B imm
                acc2 = fmaf(p2[j], vp[8 * DH_],  acc2);   // +2048 B imm
            }
        }
    } else {
        for (int k = 0; k < nv; ++k) {
            float p0 = pbuf[wave][0][k];
            float p1 = pbuf[wave][1][k];
            float p2 = pbuf[wave][2][k];
            const float* vp = vbase + vboff[k];
            acc0 = fmaf(p0, vp[0],       acc0);
            acc1 = fmaf(p1, vp[4 * DH_], acc1);
            acc2 = fmaf(p2, vp[8 * DH_], acc2);
        }
    }

    unsigned short h16, l16;
    split2(acc0, h16, l16);
    atthi[(size_t)row * D_ + (wave + 0) * DH_ + lane] = h16;
    attlo[(size_t)row * D_ + (wave + 0) * DH_ + lane] = l16;
    split2(acc1, h16, l16);
    atthi[(size_t)row * D_ + (wave + 4) * DH_ + lane] = h16;
    attlo[(size_t)row * D_ + (wave + 4) * DH_ + lane] = l16;
    split2(acc2, h16, l16);
    atthi[(size_t)row * D_ + (wave + 8) * DH_ + lane] = h16;
    attlo[(size_t)row * D_ + (wave + 8) * DH_ + lane] = l16;
}

// ---------------------------------------------------------------------------
extern "C" void kernel_launch(void* const* d_in, const int* in_sizes, int n_in,
                              void* d_out, int out_size, void* d_ws, size_t ws_size,
                              hipStream_t stream)
{
    const float* x      = (const float*)d_in[0];
    const float* wq_i   = (const float*)d_in[1];
    const float* bq_i   = (const float*)d_in[2];
    const float* wk_i   = (const float*)d_in[3];
    const float* bk_i   = (const float*)d_in[4];
    const float* w_head = (const float*)d_in[5];
    const float* w_qkv  = (const float*)d_in[6];
    const float* b_qkv  = (const float*)d_in[7];
    const float* w_out  = (const float*)d_in[8];
    const float* b_out  = (const float*)d_in[9];
    float* out = (float*)d_out;

    // Workspace layout (94,371,840 B total).  Lifetime-disjoint aliases:
    //   wqh/wql live in the scores region (dead before scores_kernel writes)
    //   woh/wol live in the scores region (written after topk consumed scores)
    //   atthi/attlo alias xhi/xlo (x splits dead after the qkv GEMM)
    char* w = (char*)d_ws;
    float* scoresb        = (float*)w;                         // 33,554,432 B
    unsigned short* wqh   = (unsigned short*)w;                //  3,538,944 B (alias)
    unsigned short* wql   = (unsigned short*)(w + 4194304);    //  (alias)
    unsigned short* woh   = (unsigned short*)(w + 8388608);    //  1,179,648 B (alias)
    unsigned short* wol   = (unsigned short*)(w + 12582912);   //  (alias)
    float* qkv            = (float*)(w + 33554432);            // 37,748,736 B
    float* qI             = (float*)(w + 71303168);            //  4,194,304 B
    float* kI             = (float*)(w + 75497472);            //  4,194,304 B
    float* routing        = (float*)(w + 79691776);            //  1,048,576 B
    int*   idxb           = (int*)  (w + 80740352);            //  1,048,576 B
    unsigned short* xhi   = (unsigned short*)(w + 81788928);   //  6,291,456 B
    unsigned short* xlo   = (unsigned short*)(w + 88080384);   //  6,291,456 B
    unsigned short* atthi = xhi;                               //  (alias)
    unsigned short* attlo = xlo;                               //  (alias)

    dim3 blk(256);

    // split x and w_qkv into bf16 hi/lo
    split_kernel<<<dim3((M_ * D_ / 4 + 255) / 256), blk, 0, stream>>>(x, xhi, xlo, M_ * D_ / 4);
    split_kernel<<<dim3((NQKV * D_ / 4 + 255) / 256), blk, 0, stream>>>(w_qkv, wqh, wql, NQKV * D_ / 4);

    // qkv projection (MFMA)
    gemm_bf16split<<<dim3(NQKV / 128, M_ / 128), blk, 0, stream>>>(xhi, xlo, wqh, wql, b_qkv, qkv, NQKV);

    // indexer projections (exact fp32)
    gemm_qiki64<<<dim3(8, M_ / 128), blk, 0, stream>>>(x, wq_i, bq_i, wk_i, bk_i, qI, kI);

    // indexer scores + top-64 (radix select)
    scores_kernel<<<dim3(T_ / 128, T_ / 128, B_), blk, 0, stream>>>(qI, kI, w_head, scoresb);
    topk_kernel<<<dim3(M_), blk, 0, stream>>>(scoresb, idxb, routing);

    // w_out split (scores region is dead now)
    split_kernel<<<dim3((D_ * D_ / 4 + 255) / 256), blk, 0, stream>>>(w_out, woh, wol, D_ * D_ / 4);

    // sparse attention -> split-bf16 output
    attn_kernel<<<dim3(M_), blk, 0, stream>>>(qkv, idxb, routing, atthi, attlo);

    // output projection (MFMA)
    gemm_bf16split<<<dim3(D_ / 128, M_ / 128), blk, 0, stream>>>(atthi, attlo, woh, wol, b_out, out, D_);
}